// Round 12
// baseline (731.821 us; speedup 1.0000x reference)
//
#include <hip/hip_runtime.h>
#include <hip/hip_bf16.h>

// ---------------------------------------------------------------------------
// SGCN: 3 x [GEMM -> normalized SpMM (+self loop) -> bias+ReLU] -> mean pool
//       -> linear classifier.
// CSR built once (padded dst-buckets), reused 3 layers.
// R3: LDS-aggregated build (global atomics are memory-side RMWs on gfx950).
// R5: gemm thread=node, acc[64] in VGPRs, W broadcast from LDS.
// R6-R10: spmm pinned at 118us / 400MB FETCH = L2 capacity misses (25.6MB
//     gather set vs 4MB per-XCD L2; floor ~230MB).
// R10: SRC-TILED spmm (7 tiles of 16K nodes = 4MB = one L2); tile-segmented
//     rows via rowseg[N][8]; waves sweep tiles in order.
// R11: fix R10 race: fused bucketF read dinv[s] of OTHER blocks' dsts before
//     they were written. Split back: bucketE1 (counts -> dinv+rowseg, grid
//     completes) then bucketE2 (cursors straight from rowseg, scatter+coef).
// ---------------------------------------------------------------------------

#define WS_ALIGN(x) (((x) + 255) & ~(size_t)255)
#define POOL_CHUNK 128
#define ECHUNK 8192                    // edges per build block
#define BSHIFT 5                       // 32 dst nodes per bucket
#define BMASK  ((1 << BSHIFT) - 1)
#define SRCBITS 17                     // N=100000 < 2^17
#define BCAP 1280                      // bucket capacity (mean 1024 + 8 sigma)
#define TILE_SHIFT 14                  // 16384 srcs per tile = 4MB HW = L2
#define NTILE 7                        // ceil(100000 / 16384)

typedef float f32x4 __attribute__((ext_vector_type(4)));

// ---- build 1: scatter edges into padded bucket regions --------------------
__global__ __launch_bounds__(512)
void scatterD_kernel(const int* __restrict__ src, const int* __restrict__ dst,
                     const float* __restrict__ ea, int E, int NB,
                     int* __restrict__ bcursor, int2* __restrict__ sbuf) {
    extern __shared__ int sh[];
    for (int i = threadIdx.x; i < NB; i += 512) sh[i] = 0;
    __syncthreads();
    int beg = blockIdx.x * ECHUNK, end = min(beg + ECHUNK, E);
    for (int i = beg + threadIdx.x; i < end; i += 512)
        atomicAdd(&sh[dst[i] >> BSHIFT], 1);
    __syncthreads();
    for (int i = threadIdx.x; i < NB; i += 512) {
        int c = sh[i];
        sh[i] = c ? (i * BCAP + atomicAdd(&bcursor[i], c)) : 0;
    }
    __syncthreads();
    for (int i = beg + threadIdx.x; i < end; i += 512) {
        int s = src[i], d = dst[i];
        int pos = atomicAdd(&sh[d >> BSHIFT], 1);        // LDS cursor
        sbuf[pos] = make_int2(s | ((d & BMASK) << SRCBITS),
                              __float_as_int(ea[i]));
    }
}

// ---- build 2: per-(dst,tile) counts -> dinv + tile-segmented rowseg -------
__global__ __launch_bounds__(256)
void bucketE1_kernel(const int2* __restrict__ sbuf, const int* __restrict__ bcnt,
                     int N, float* __restrict__ dinv, int* __restrict__ rowseg) {
    __shared__ int scnt[32 * 8];
    for (int i = threadIdx.x; i < 32 * 8; i += 256) scnt[i] = 0;
    __syncthreads();
    int b = blockIdx.x;
    int base = b * BCAP, cnt = bcnt[b];
    for (int j = threadIdx.x; j < cnt; j += 256) {
        int2 e = sbuf[base + j];
        int dl = (e.x >> SRCBITS) & BMASK;
        int t  = (e.x & ((1 << SRCBITS) - 1)) >> TILE_SHIFT;
        atomicAdd(&scnt[dl * 8 + t], 1);
    }
    __syncthreads();
    if (threadIdx.x < 32) {
        int dl = threadIdx.x;
        int deg = 0;
        #pragma unroll
        for (int t = 0; t < NTILE; ++t) deg += scnt[dl * 8 + t];
        int x = deg;                                     // wave prefix
        #pragma unroll
        for (int off = 1; off < 32; off <<= 1) {
            int tt = __shfl_up(x, off);
            if (dl >= off) x += tt;
        }
        int rb = base + x - deg;                         // row start
        int d = (b << BSHIFT) + dl;
        if (d < N) {
            dinv[d] = 1.0f / sqrtf((float)(deg + 1));    // +1 = self loop
            int* rs = rowseg + (size_t)d * 8;
            int off = rb;
            #pragma unroll
            for (int t = 0; t < NTILE; ++t) { rs[t] = off; off += scnt[dl * 8 + t]; }
            rs[NTILE] = off;                             // row end (slot 7)
        }
    }
}

// ---- build 3: scatter to cpair (cursors from rowseg; dinv fully written) --
__global__ __launch_bounds__(256)
void bucketE2_kernel(const int2* __restrict__ sbuf, const int* __restrict__ bcnt,
                     const float* __restrict__ dinv, int N,
                     const int* __restrict__ rowseg, int2* __restrict__ cpair) {
    __shared__ int scur[32 * 8];
    __shared__ float sdinv[32];
    int b = blockIdx.x;
    int dbase = b << BSHIFT;
    for (int i = threadIdx.x; i < 32 * 8; i += 256) {
        int dl = i >> 3, t = i & 7;
        int d = dbase + dl;
        scur[i] = (d < N && t < NTILE) ? rowseg[(size_t)d * 8 + t] : 0;
    }
    if (threadIdx.x < 32) {
        int d = dbase + threadIdx.x;
        sdinv[threadIdx.x] = (d < N) ? dinv[d] : 0.f;
    }
    __syncthreads();
    int base = b * BCAP, cnt = bcnt[b];
    for (int j = threadIdx.x; j < cnt; j += 256) {
        int2 e = sbuf[base + j];
        int dl = (e.x >> SRCBITS) & BMASK;
        int s  = e.x & ((1 << SRCBITS) - 1);
        float c = dinv[s] * sdinv[dl] * expf(-__int_as_float(e.y));
        int pos = atomicAdd(&scur[dl * 8 + (s >> TILE_SHIFT)], 1);
        cpair[pos] = make_int2(s, __float_as_int(c));
    }
}

// ---- dense GEMM: Y[N,64] = X[N,K] @ W[K,64] --------------------------------
template <int K>
__global__ __launch_bounds__(256)
void gemm3_kernel(const float* __restrict__ X, const float* __restrict__ W,
                  float* __restrict__ Y, int N) {
    __shared__ float sW[K * 64];
    for (int i = threadIdx.x; i < K * 64; i += 256) sW[i] = W[i];
    __syncthreads();
    int node = blockIdx.x * 256 + threadIdx.x;
    if (node >= N) return;
    const float4* xr = reinterpret_cast<const float4*>(X + (size_t)node * K);
    float acc[64];
    #pragma unroll
    for (int c = 0; c < 64; ++c) acc[c] = 0.f;
    #pragma unroll 2
    for (int k4 = 0; k4 < K / 4; ++k4) {
        float4 xv = xr[k4];
        #pragma unroll
        for (int j = 0; j < 4; ++j) {
            float xs = (j == 0) ? xv.x : (j == 1) ? xv.y : (j == 2) ? xv.z : xv.w;
            const float4* wr =
                reinterpret_cast<const float4*>(sW + (k4 * 4 + j) * 64);
            #pragma unroll
            for (int c4 = 0; c4 < 16; ++c4) {
                float4 wv = wr[c4];
                acc[4 * c4 + 0] = fmaf(xs, wv.x, acc[4 * c4 + 0]);
                acc[4 * c4 + 1] = fmaf(xs, wv.y, acc[4 * c4 + 1]);
                acc[4 * c4 + 2] = fmaf(xs, wv.z, acc[4 * c4 + 2]);
                acc[4 * c4 + 3] = fmaf(xs, wv.w, acc[4 * c4 + 3]);
            }
        }
    }
    float4* yr = reinterpret_cast<float4*>(Y + (size_t)node * 64);
    #pragma unroll
    for (int c4 = 0; c4 < 16; ++c4)
        yr[c4] = make_float4(acc[4 * c4 + 0], acc[4 * c4 + 1],
                             acc[4 * c4 + 2], acc[4 * c4 + 3]);
}

// ---- SpMM common: one edge's contribution to a float4 of channels ---------
__device__ __forceinline__ void quad_acc(const int2* __restrict__ cpair,
                                         int eidx, const float* __restrict__ HW,
                                         int chb, float4& acc, bool ok) {
    long long pv = __builtin_nontemporal_load(
        reinterpret_cast<const long long*>(cpair) + eidx);
    int   s = (int)(pv & 0xffffffffLL);
    float c = __int_as_float((int)(pv >> 32));
    c = ok ? c : 0.f;
    const float4 hv = *reinterpret_cast<const float4*>(
        HW + (size_t)s * 64 + chb);
    acc.x = fmaf(c, hv.x, acc.x);
    acc.y = fmaf(c, hv.y, acc.y);
    acc.z = fmaf(c, hv.z, acc.z);
    acc.w = fmaf(c, hv.w, acc.w);
}

// ---- SpMM v5: src-tiled. lane=(edge-slot 0..3, chan-quad 0..15) -----------
// All waves sweep src-tiles t=0..6 in order; register acc persists.
__global__ __launch_bounds__(256)
void spmm5_kernel(const float* __restrict__ HW,
                  const int* __restrict__ rowseg,
                  const int2* __restrict__ cpair,
                  const float* __restrict__ dinv,
                  const float* __restrict__ bias,
                  float* __restrict__ OUT, int N) {
    int node = blockIdx.x * 4 + (threadIdx.x >> 6);
    if (node >= N) return;
    int lane = threadIdx.x & 63;
    int g    = lane >> 4;              // edge slot
    int chb  = (lane & 15) * 4;        // channel base (float4)
    const int4* sp = reinterpret_cast<const int4*>(rowseg + (size_t)node * 8);
    int4 sa = sp[0], sb = sp[1];
    int seg[8] = {sa.x, sa.y, sa.z, sa.w, sb.x, sb.y, sb.z, sb.w};
    float di = dinv[node];

    float4 a0 = make_float4(0.f, 0.f, 0.f, 0.f);
    float4 a1 = make_float4(0.f, 0.f, 0.f, 0.f);
    float4 hs = *reinterpret_cast<const float4*>(HW + (size_t)node * 64 + chb);
    if (g == 0) {
        float s2 = di * di;
        a0 = make_float4(s2 * hs.x, s2 * hs.y, s2 * hs.z, s2 * hs.w);
    }

    #pragma unroll
    for (int t = 0; t < NTILE; ++t) {
        int sbeg = seg[t], send = seg[t + 1];
        for (int j = sbeg; j < send; j += 8) {
            int i0 = j + g;
            quad_acc(cpair, i0 < send ? i0 : sbeg, HW, chb, a0, i0 < send);
            if (j + 4 < send) {
                int i1 = j + 4 + g;
                quad_acc(cpair, i1 < send ? i1 : sbeg, HW, chb, a1, i1 < send);
            }
        }
    }

    float4 r = make_float4(a0.x + a1.x, a0.y + a1.y, a0.z + a1.z, a0.w + a1.w);
    r.x += __shfl_xor(r.x, 32); r.y += __shfl_xor(r.y, 32);
    r.z += __shfl_xor(r.z, 32); r.w += __shfl_xor(r.w, 32);
    r.x += __shfl_xor(r.x, 16); r.y += __shfl_xor(r.y, 16);
    r.z += __shfl_xor(r.z, 16); r.w += __shfl_xor(r.w, 16);

    if (lane < 16) {
        float4 bv = *reinterpret_cast<const float4*>(bias + chb);
        f32x4 o;
        o.x = fmaxf(r.x + bv.x, 0.f);
        o.y = fmaxf(r.y + bv.y, 0.f);
        o.z = fmaxf(r.z + bv.z, 0.f);
        o.w = fmaxf(r.w + bv.w, 0.f);
        __builtin_nontemporal_store(o, reinterpret_cast<f32x4*>(
            OUT + (size_t)node * 64 + chb));
    }
}

// ---- pool stage 1: per-chunk per-graph partial sums -----------------------
__global__ __launch_bounds__(256)
void pool1_kernel(const float* __restrict__ H, const int* __restrict__ batch,
                  int N, int B, float* __restrict__ partial) {
    __shared__ float part[4][16][64];
    int lane = threadIdx.x & 63, wid = threadIdx.x >> 6;
    for (int g = 0; g < 16; ++g) part[wid][g][lane] = 0.f;
    int beg = blockIdx.x * POOL_CHUNK;
    int end = min(beg + POOL_CHUNK, N);
    float acc = 0.f; int cur = -1;
    for (int v = beg + wid; v < end; v += 4) {
        int g = batch[v];
        if (g != cur) {
            if (cur >= 0) part[wid][cur][lane] += acc;
            cur = g; acc = 0.f;
        }
        acc += H[(size_t)v * 64 + lane];
    }
    if (cur >= 0) part[wid][cur][lane] += acc;
    __syncthreads();
    float* outp = partial + (size_t)blockIdx.x * B * 64;
    for (int idx = threadIdx.x; idx < B * 64; idx += 256) {
        int g = idx >> 6, l = idx & 63;
        outp[idx] = part[0][g][l] + part[1][g][l] + part[2][g][l] + part[3][g][l];
    }
}

// ---- pool stage 2: fixed-order reduce over blocks, divide by count --------
__global__ __launch_bounds__(256)
void pool2_kernel(const float* __restrict__ partial, int nblk, int B,
                  const int* __restrict__ batch, int N,
                  float* __restrict__ pooled) {
    int g = blockIdx.x;
    int lane = threadIdx.x & 63, wid = threadIdx.x >> 6;
    float acc = 0.f;
    for (int b = wid; b < nblk; b += 4)
        acc += partial[(size_t)b * B * 64 + g * 64 + lane];
    __shared__ float sacc[4][64];
    sacc[wid][lane] = acc;
    __syncthreads();
    if (wid == 0) {
        int lo = 0, hi = N;
        while (lo < hi) { int m = (lo + hi) >> 1; if (batch[m] < g) lo = m + 1; else hi = m; }
        int s0 = lo;
        lo = 0; hi = N;
        while (lo < hi) { int m = (lo + hi) >> 1; if (batch[m] < g + 1) lo = m + 1; else hi = m; }
        float cnt = (float)(lo - s0);
        float s = sacc[0][lane] + sacc[1][lane] + sacc[2][lane] + sacc[3][lane];
        pooled[g * 64 + lane] = s / fmaxf(cnt, 1.0f);
    }
}

// ---- classifier: out[B,C] = pooled[B,64] @ Wc[64,C] + bc ------------------
__global__ __launch_bounds__(256)
void final_kernel(const float* __restrict__ pooled, const float* __restrict__ Wc,
                  const float* __restrict__ bc, float* __restrict__ out, int C) {
    int b = blockIdx.x;
    __shared__ float sp[64];
    if (threadIdx.x < 64) sp[threadIdx.x] = pooled[b * 64 + threadIdx.x];
    __syncthreads();
    for (int c = threadIdx.x; c < C; c += blockDim.x) {
        float acc = bc[c];
        #pragma unroll
        for (int k = 0; k < 64; ++k) acc = fmaf(sp[k], Wc[k * C + c], acc);
        out[b * C + c] = acc;
    }
}

extern "C" void kernel_launch(void* const* d_in, const int* in_sizes, int n_in,
                              void* d_out, int out_size, void* d_ws, size_t ws_size,
                              hipStream_t stream) {
    const float* x     = (const float*)d_in[0];
    const int*   esrc  = (const int*)  d_in[1];
    const int*   edst  = (const int*)  d_in[2];
    const float* ea    = (const float*)d_in[3];
    const int*   batch = (const int*)  d_in[4];
    const float* W0 = (const float*)d_in[5];  const float* b0 = (const float*)d_in[6];
    const float* W1 = (const float*)d_in[7];  const float* b1 = (const float*)d_in[8];
    const float* W2 = (const float*)d_in[9];  const float* b2 = (const float*)d_in[10];
    const float* Wc = (const float*)d_in[11]; const float* bc = (const float*)d_in[12];

    const int N = in_sizes[4];
    const int E = in_sizes[1];
    const int C = in_sizes[12];            // 196
    const int B = out_size / C;            // 16
    (void)n_in; (void)ws_size;

    const int NB        = (N + BMASK) >> BSHIFT;              // dst buckets
    const int nchunk    = (E + ECHUNK - 1) / ECHUNK;          // build chunks
    const int nblk_pool = (N + POOL_CHUNK - 1) / POOL_CHUNK;
    const size_t PADDED = (size_t)NB * BCAP;                  // padded entries

    // ---- carve workspace ----
    char* w = (char*)d_ws;
    auto alloc = [&](size_t bytes) { void* p = (void*)w; w += WS_ALIGN(bytes); return p; };
    float* d_dinv    = (float*)alloc((size_t)N * 4);
    int*   d_rowseg  = (int*)  alloc((size_t)N * 8 * 4);
    int*   d_bcursor = (int*)  alloc((size_t)NB * 4);
    int2*  d_cpair   = (int2*) alloc(PADDED * 8);
    float* d_hA      = (float*)alloc((size_t)N * 64 * 4);
    size_t tmp_bytes = (size_t)N * 64 * 4;
    if (PADDED * 8 > tmp_bytes) tmp_bytes = PADDED * 8;
    float* d_tmp     = (float*)alloc(tmp_bytes);
    float* d_partial = (float*)alloc((size_t)nblk_pool * B * 64 * 4);
    float* d_pool    = (float*)alloc((size_t)B * 64 * 4);
    int2*  d_sbuf    = (int2*)d_tmp;   // alias: staging dead before first gemm

    // ---- build CSR (padded buckets, tile-segmented rows) ----
    hipMemsetAsync(d_bcursor, 0, (size_t)NB * 4, stream);
    scatterD_kernel<<<nchunk, 512, NB * 4, stream>>>(esrc, edst, ea, E, NB,
                                                     d_bcursor, d_sbuf);
    bucketE1_kernel<<<NB, 256, 0, stream>>>(d_sbuf, d_bcursor, N, d_dinv, d_rowseg);
    bucketE2_kernel<<<NB, 256, 0, stream>>>(d_sbuf, d_bcursor, d_dinv, N,
                                            d_rowseg, d_cpair);

    const int nblk = (N + 3) / 4;
    const int gblk = (N + 255) / 256;
    // ---- layer 0 (K=128) ----
    gemm3_kernel<128><<<gblk, 256, 0, stream>>>(x, W0, d_tmp, N);
    spmm5_kernel<<<nblk, 256, 0, stream>>>(d_tmp, d_rowseg, d_cpair,
                                           d_dinv, b0, d_hA, N);
    // ---- layer 1 (K=64) ----
    gemm3_kernel<64><<<gblk, 256, 0, stream>>>(d_hA, W1, d_tmp, N);
    spmm5_kernel<<<nblk, 256, 0, stream>>>(d_tmp, d_rowseg, d_cpair,
                                           d_dinv, b1, d_hA, N);
    // ---- layer 2 (K=64) ----
    gemm3_kernel<64><<<gblk, 256, 0, stream>>>(d_hA, W2, d_tmp, N);
    spmm5_kernel<<<nblk, 256, 0, stream>>>(d_tmp, d_rowseg, d_cpair,
                                           d_dinv, b2, d_hA, N);

    // ---- pool + classifier ----
    pool1_kernel<<<nblk_pool, 256, 0, stream>>>(d_hA, batch, N, B, d_partial);
    pool2_kernel<<<B, 256, 0, stream>>>(d_partial, nblk_pool, B, batch, N, d_pool);
    final_kernel<<<B, 256, 0, stream>>>(d_pool, Wc, bc, (float*)d_out, C);
}

// Round 13
// 641.041 us; speedup vs baseline: 1.1416x; 1.1416x over previous
//
#include <hip/hip_runtime.h>
#include <hip/hip_bf16.h>

// ---------------------------------------------------------------------------
// SGCN: 3 x [GEMM -> normalized SpMM (+self loop) -> bias+ReLU] -> mean pool
//       -> linear classifier.
// CSR built once (padded dst-buckets), reused 3 layers.
// R3: LDS-aggregated build (global atomics are memory-side RMWs on gfx950).
// R5: gemm thread=node, acc[64] in VGPRs, W broadcast from LDS.
// R6-R11: spmm is L2 line-traffic bound at ~118us/400MB (random graph,
//     25.6MB gather set vs 4MB/XCD L2). Channel-split (R7) and src-tiling
//     (R10/11, co-phasing failed: FETCH 410MB, 145us) both falsified ->
//     spmm4 full-row is the floor. Reverted.
// R12: fuse next-layer GEMM into spmm epilogue (layers 0,1): wave holds the
//     full h-row after shfl-reduce; LDS-stage h + W_next, each g-group does
//     k in [16g,16g+16), reduce over g, NT-store hW. Deletes 2 gemm64
//     dispatches; VALU work hides under gather stalls (VALUBusy was 21%).
// ---------------------------------------------------------------------------

#define WS_ALIGN(x) (((x) + 255) & ~(size_t)255)
#define POOL_CHUNK 128
#define ECHUNK 8192                    // edges per build block
#define BSHIFT 5                       // 32 dst nodes per bucket
#define BMASK  ((1 << BSHIFT) - 1)
#define SRCBITS 17                     // N=100000 < 2^17
#define BCAP 1280                      // bucket capacity (mean 1024 + 8 sigma)

typedef float f32x4 __attribute__((ext_vector_type(4)));

// ---- build 1: scatter edges into padded bucket regions --------------------
__global__ __launch_bounds__(512)
void scatterD_kernel(const int* __restrict__ src, const int* __restrict__ dst,
                     const float* __restrict__ ea, int E, int NB,
                     int* __restrict__ bcursor, int2* __restrict__ sbuf) {
    extern __shared__ int sh[];
    for (int i = threadIdx.x; i < NB; i += 512) sh[i] = 0;
    __syncthreads();
    int beg = blockIdx.x * ECHUNK, end = min(beg + ECHUNK, E);
    for (int i = beg + threadIdx.x; i < end; i += 512)
        atomicAdd(&sh[dst[i] >> BSHIFT], 1);
    __syncthreads();
    for (int i = threadIdx.x; i < NB; i += 512) {
        int c = sh[i];
        sh[i] = c ? (i * BCAP + atomicAdd(&bcursor[i], c)) : 0;
    }
    __syncthreads();
    for (int i = beg + threadIdx.x; i < end; i += 512) {
        int s = src[i], d = dst[i];
        int pos = atomicAdd(&sh[d >> BSHIFT], 1);        // LDS cursor
        sbuf[pos] = make_int2(s | ((d & BMASK) << SRCBITS),
                              __float_as_int(ea[i]));
    }
}

// ---- build 2: per-bucket degree count -> dinv, rowbeg/rowend --------------
__global__ __launch_bounds__(256)
void bucketE1_kernel(const int2* __restrict__ sbuf, const int* __restrict__ bcnt,
                     int N, float* __restrict__ dinv,
                     int* __restrict__ rowbeg, int* __restrict__ rowend) {
    __shared__ int dcount[32];
    if (threadIdx.x < 32) dcount[threadIdx.x] = 0;
    __syncthreads();
    int b = blockIdx.x;
    int base = b * BCAP, cnt = bcnt[b];
    for (int j = threadIdx.x; j < cnt; j += 256)
        atomicAdd(&dcount[(sbuf[base + j].x >> SRCBITS) & BMASK], 1);
    __syncthreads();
    if (threadIdx.x < 32) {
        int c = dcount[threadIdx.x];
        int x = c;
        #pragma unroll
        for (int off = 1; off < 32; off <<= 1) {
            int t = __shfl_up(x, off);
            if (threadIdx.x >= off) x += t;
        }
        int d = (b << BSHIFT) + threadIdx.x;
        if (d < N) {
            int rb = base + x - c;                       // exclusive prefix
            rowbeg[d] = rb;
            rowend[d] = rb + c;
            dinv[d]   = 1.0f / sqrtf((float)(c + 1));    // +1 = self loop
        }
    }
}

// ---- build 3: within-bucket scatter to final CSR + coefficient ------------
__global__ __launch_bounds__(256)
void bucketE2_kernel(const int2* __restrict__ sbuf, const int* __restrict__ bcnt,
                     const float* __restrict__ dinv, int N,
                     const int* __restrict__ rowbeg, int2* __restrict__ cpair) {
    __shared__ int cur[32];
    __shared__ float sdinv[32];
    int b = blockIdx.x;
    int dbase = b << BSHIFT;
    if (threadIdx.x < 32) {
        int d = dbase + threadIdx.x;
        cur[threadIdx.x]   = (d < N) ? rowbeg[d] : 0;
        sdinv[threadIdx.x] = (d < N) ? dinv[d] : 0.f;
    }
    __syncthreads();
    int base = b * BCAP, cnt = bcnt[b];
    for (int j = threadIdx.x; j < cnt; j += 256) {
        int2 e = sbuf[base + j];
        int dl = (e.x >> SRCBITS) & BMASK;
        int s  = e.x & ((1 << SRCBITS) - 1);
        float c = dinv[s] * sdinv[dl] * expf(-__int_as_float(e.y));
        int pos = atomicAdd(&cur[dl], 1);                // LDS cursor
        cpair[pos] = make_int2(s, __float_as_int(c));
    }
}

// ---- dense GEMM: Y[N,64] = X[N,K] @ W[K,64] (layer 0 only) -----------------
template <int K>
__global__ __launch_bounds__(256)
void gemm3_kernel(const float* __restrict__ X, const float* __restrict__ W,
                  float* __restrict__ Y, int N) {
    __shared__ float sW[K * 64];
    for (int i = threadIdx.x; i < K * 64; i += 256) sW[i] = W[i];
    __syncthreads();
    int node = blockIdx.x * 256 + threadIdx.x;
    if (node >= N) return;
    const float4* xr = reinterpret_cast<const float4*>(X + (size_t)node * K);
    float acc[64];
    #pragma unroll
    for (int c = 0; c < 64; ++c) acc[c] = 0.f;
    #pragma unroll 2
    for (int k4 = 0; k4 < K / 4; ++k4) {
        float4 xv = xr[k4];
        #pragma unroll
        for (int j = 0; j < 4; ++j) {
            float xs = (j == 0) ? xv.x : (j == 1) ? xv.y : (j == 2) ? xv.z : xv.w;
            const float4* wr =
                reinterpret_cast<const float4*>(sW + (k4 * 4 + j) * 64);
            #pragma unroll
            for (int c4 = 0; c4 < 16; ++c4) {
                float4 wv = wr[c4];
                acc[4 * c4 + 0] = fmaf(xs, wv.x, acc[4 * c4 + 0]);
                acc[4 * c4 + 1] = fmaf(xs, wv.y, acc[4 * c4 + 1]);
                acc[4 * c4 + 2] = fmaf(xs, wv.z, acc[4 * c4 + 2]);
                acc[4 * c4 + 3] = fmaf(xs, wv.w, acc[4 * c4 + 3]);
            }
        }
    }
    float4* yr = reinterpret_cast<float4*>(Y + (size_t)node * 64);
    #pragma unroll
    for (int c4 = 0; c4 < 16; ++c4)
        yr[c4] = make_float4(acc[4 * c4 + 0], acc[4 * c4 + 1],
                             acc[4 * c4 + 2], acc[4 * c4 + 3]);
}

// ---- SpMM common: one edge's contribution to a float4 of channels ---------
__device__ __forceinline__ void quad_acc(const int2* __restrict__ cpair,
                                         int eidx, const float* __restrict__ HW,
                                         int chb, float4& acc, bool ok) {
    long long pv = __builtin_nontemporal_load(
        reinterpret_cast<const long long*>(cpair) + eidx);
    int   s = (int)(pv & 0xffffffffLL);
    float c = __int_as_float((int)(pv >> 32));
    c = ok ? c : 0.f;
    const float4 hv = *reinterpret_cast<const float4*>(
        HW + (size_t)s * 64 + chb);
    acc.x = fmaf(c, hv.x, acc.x);
    acc.y = fmaf(c, hv.y, acc.y);
    acc.z = fmaf(c, hv.z, acc.z);
    acc.w = fmaf(c, hv.w, acc.w);
}

// ---- SpMM v6: gather (as spmm4) + optional fused next-layer GEMM ----------
// lane=(edge-slot g 0..3, chan-quad q 0..15). After shfl reduce, every lane
// holds the full h row for its q (replicated over g). FUSEW: stage h in LDS,
// group g computes k in [16g,16g+16) of h@Wn, reduce over g, NT-store hW.
template <bool FUSEW>
__global__ __launch_bounds__(256)
void spmmG_kernel(const float* __restrict__ HW,
                  const int* __restrict__ rowbeg,
                  const int* __restrict__ rowend,
                  const int2* __restrict__ cpair,
                  const float* __restrict__ dinv,
                  const float* __restrict__ bias,
                  const float* __restrict__ Wn,
                  float* __restrict__ OUT, int N) {
    __shared__ float sW[FUSEW ? 64 * 64 : 1];
    __shared__ float hrow[4][64];
    if (FUSEW) {
        for (int i = threadIdx.x; i < 64 * 64; i += 256) sW[i] = Wn[i];
        __syncthreads();
    }
    const int lane = threadIdx.x & 63, wid = threadIdx.x >> 6;
    const int g = lane >> 4, chb = (lane & 15) * 4;
    const int nquad = (N + 3) >> 2;

    for (int quad = blockIdx.x; quad < nquad; quad += gridDim.x) {
        int node = quad * 4 + wid;
        if (node >= N) continue;
        int beg = rowbeg[node], end = rowend[node];
        float di = dinv[node];

        float4 a0 = make_float4(0.f, 0.f, 0.f, 0.f);
        float4 a1 = make_float4(0.f, 0.f, 0.f, 0.f);
        float4 hs = *reinterpret_cast<const float4*>(HW + (size_t)node * 64 + chb);
        if (g == 0) {
            float s2 = di * di;
            a0 = make_float4(s2 * hs.x, s2 * hs.y, s2 * hs.z, s2 * hs.w);
        }
        int j = beg;
        for (; j + 8 <= end; j += 8) {
            quad_acc(cpair, j + g,     HW, chb, a0, true);
            quad_acc(cpair, j + 4 + g, HW, chb, a1, true);
        }
        for (; j < end; j += 4) {
            int e = j + g;
            bool ok = e < end;
            quad_acc(cpair, ok ? e : beg, HW, chb, a0, ok);
        }
        float4 r = make_float4(a0.x + a1.x, a0.y + a1.y, a0.z + a1.z, a0.w + a1.w);
        r.x += __shfl_xor(r.x, 32); r.y += __shfl_xor(r.y, 32);
        r.z += __shfl_xor(r.z, 32); r.w += __shfl_xor(r.w, 32);
        r.x += __shfl_xor(r.x, 16); r.y += __shfl_xor(r.y, 16);
        r.z += __shfl_xor(r.z, 16); r.w += __shfl_xor(r.w, 16);

        float4 bv = *reinterpret_cast<const float4*>(bias + chb);
        float4 h;
        h.x = fmaxf(r.x + bv.x, 0.f);
        h.y = fmaxf(r.y + bv.y, 0.f);
        h.z = fmaxf(r.z + bv.z, 0.f);
        h.w = fmaxf(r.w + bv.w, 0.f);

        if (!FUSEW) {
            if (lane < 16) {
                f32x4 o = {h.x, h.y, h.z, h.w};
                __builtin_nontemporal_store(o, reinterpret_cast<f32x4*>(
                    OUT + (size_t)node * 64 + chb));
            }
        } else {
            // stage full h row (g==0 lanes cover q=0..15)
            if (g == 0) *reinterpret_cast<float4*>(&hrow[wid][chb]) = h;
            // same-wave LDS RAW: compiler inserts the lgkmcnt wait
            float4 y = make_float4(0.f, 0.f, 0.f, 0.f);
            #pragma unroll
            for (int kk = 0; kk < 16; ++kk) {
                int k = g * 16 + kk;
                float hk = hrow[wid][k];
                const float4 wv = *reinterpret_cast<const float4*>(&sW[k * 64 + chb]);
                y.x = fmaf(hk, wv.x, y.x);
                y.y = fmaf(hk, wv.y, y.y);
                y.z = fmaf(hk, wv.z, y.z);
                y.w = fmaf(hk, wv.w, y.w);
            }
            y.x += __shfl_xor(y.x, 32); y.y += __shfl_xor(y.y, 32);
            y.z += __shfl_xor(y.z, 32); y.w += __shfl_xor(y.w, 32);
            y.x += __shfl_xor(y.x, 16); y.y += __shfl_xor(y.y, 16);
            y.z += __shfl_xor(y.z, 16); y.w += __shfl_xor(y.w, 16);
            if (lane < 16) {
                f32x4 o = {y.x, y.y, y.z, y.w};
                __builtin_nontemporal_store(o, reinterpret_cast<f32x4*>(
                    OUT + (size_t)node * 64 + chb));
            }
        }
    }
}

// ---- pool stage 1: per-chunk per-graph partial sums -----------------------
__global__ __launch_bounds__(256)
void pool1_kernel(const float* __restrict__ H, const int* __restrict__ batch,
                  int N, int B, float* __restrict__ partial) {
    __shared__ float part[4][16][64];
    int lane = threadIdx.x & 63, wid = threadIdx.x >> 6;
    for (int g = 0; g < 16; ++g) part[wid][g][lane] = 0.f;
    int beg = blockIdx.x * POOL_CHUNK;
    int end = min(beg + POOL_CHUNK, N);
    float acc = 0.f; int cur = -1;
    for (int v = beg + wid; v < end; v += 4) {
        int g = batch[v];
        if (g != cur) {
            if (cur >= 0) part[wid][cur][lane] += acc;
            cur = g; acc = 0.f;
        }
        acc += H[(size_t)v * 64 + lane];
    }
    if (cur >= 0) part[wid][cur][lane] += acc;
    __syncthreads();
    float* outp = partial + (size_t)blockIdx.x * B * 64;
    for (int idx = threadIdx.x; idx < B * 64; idx += 256) {
        int g = idx >> 6, l = idx & 63;
        outp[idx] = part[0][g][l] + part[1][g][l] + part[2][g][l] + part[3][g][l];
    }
}

// ---- pool stage 2: fixed-order reduce over blocks, divide by count --------
__global__ __launch_bounds__(256)
void pool2_kernel(const float* __restrict__ partial, int nblk, int B,
                  const int* __restrict__ batch, int N,
                  float* __restrict__ pooled) {
    int g = blockIdx.x;
    int lane = threadIdx.x & 63, wid = threadIdx.x >> 6;
    float acc = 0.f;
    for (int b = wid; b < nblk; b += 4)
        acc += partial[(size_t)b * B * 64 + g * 64 + lane];
    __shared__ float sacc[4][64];
    sacc[wid][lane] = acc;
    __syncthreads();
    if (wid == 0) {
        int lo = 0, hi = N;
        while (lo < hi) { int m = (lo + hi) >> 1; if (batch[m] < g) lo = m + 1; else hi = m; }
        int s0 = lo;
        lo = 0; hi = N;
        while (lo < hi) { int m = (lo + hi) >> 1; if (batch[m] < g + 1) lo = m + 1; else hi = m; }
        float cnt = (float)(lo - s0);
        float s = sacc[0][lane] + sacc[1][lane] + sacc[2][lane] + sacc[3][lane];
        pooled[g * 64 + lane] = s / fmaxf(cnt, 1.0f);
    }
}

// ---- classifier: out[B,C] = pooled[B,64] @ Wc[64,C] + bc ------------------
__global__ __launch_bounds__(256)
void final_kernel(const float* __restrict__ pooled, const float* __restrict__ Wc,
                  const float* __restrict__ bc, float* __restrict__ out, int C) {
    int b = blockIdx.x;
    __shared__ float sp[64];
    if (threadIdx.x < 64) sp[threadIdx.x] = pooled[b * 64 + threadIdx.x];
    __syncthreads();
    for (int c = threadIdx.x; c < C; c += blockDim.x) {
        float acc = bc[c];
        #pragma unroll
        for (int k = 0; k < 64; ++k) acc = fmaf(sp[k], Wc[k * C + c], acc);
        out[b * C + c] = acc;
    }
}

extern "C" void kernel_launch(void* const* d_in, const int* in_sizes, int n_in,
                              void* d_out, int out_size, void* d_ws, size_t ws_size,
                              hipStream_t stream) {
    const float* x     = (const float*)d_in[0];
    const int*   esrc  = (const int*)  d_in[1];
    const int*   edst  = (const int*)  d_in[2];
    const float* ea    = (const float*)d_in[3];
    const int*   batch = (const int*)  d_in[4];
    const float* W0 = (const float*)d_in[5];  const float* b0 = (const float*)d_in[6];
    const float* W1 = (const float*)d_in[7];  const float* b1 = (const float*)d_in[8];
    const float* W2 = (const float*)d_in[9];  const float* b2 = (const float*)d_in[10];
    const float* Wc = (const float*)d_in[11]; const float* bc = (const float*)d_in[12];

    const int N = in_sizes[4];
    const int E = in_sizes[1];
    const int C = in_sizes[12];            // 196
    const int B = out_size / C;            // 16
    (void)n_in; (void)ws_size;

    const int NB        = (N + BMASK) >> BSHIFT;              // dst buckets
    const int nchunk    = (E + ECHUNK - 1) / ECHUNK;          // build chunks
    const int nblk_pool = (N + POOL_CHUNK - 1) / POOL_CHUNK;
    const size_t PADDED = (size_t)NB * BCAP;                  // padded entries

    // ---- carve workspace ----
    char* w = (char*)d_ws;
    auto alloc = [&](size_t bytes) { void* p = (void*)w; w += WS_ALIGN(bytes); return p; };
    float* d_dinv    = (float*)alloc((size_t)N * 4);
    int*   d_rowbeg  = (int*)  alloc((size_t)N * 4);
    int*   d_rowend  = (int*)  alloc((size_t)N * 4);
    int*   d_bcursor = (int*)  alloc((size_t)NB * 4);
    int2*  d_cpair   = (int2*) alloc(PADDED * 8);
    float* d_hA      = (float*)alloc((size_t)N * 64 * 4);
    size_t tmp_bytes = (size_t)N * 64 * 4;
    if (PADDED * 8 > tmp_bytes) tmp_bytes = PADDED * 8;
    float* d_tmp     = (float*)alloc(tmp_bytes);
    float* d_partial = (float*)alloc((size_t)nblk_pool * B * 64 * 4);
    float* d_pool    = (float*)alloc((size_t)B * 64 * 4);
    int2*  d_sbuf    = (int2*)d_tmp;   // alias: staging dead before first gemm

    // ---- build CSR (padded buckets; no global histogram / scan) ----
    hipMemsetAsync(d_bcursor, 0, (size_t)NB * 4, stream);
    scatterD_kernel<<<nchunk, 512, NB * 4, stream>>>(esrc, edst, ea, E, NB,
                                                     d_bcursor, d_sbuf);
    bucketE1_kernel<<<NB, 256, 0, stream>>>(d_sbuf, d_bcursor, N, d_dinv,
                                            d_rowbeg, d_rowend);
    bucketE2_kernel<<<NB, 256, 0, stream>>>(d_sbuf, d_bcursor, d_dinv, N,
                                            d_rowbeg, d_cpair);

    const int gblk = (N + 255) / 256;
    const int sgrid = 4096;            // grid-stride; W staged once per block
    // ---- layer 0: x@W0 -> spmm(+b0,relu) fused @W1 -> d_hA = h0@W1 ----
    gemm3_kernel<128><<<gblk, 256, 0, stream>>>(x, W0, d_tmp, N);
    spmmG_kernel<true><<<sgrid, 256, 0, stream>>>(d_tmp, d_rowbeg, d_rowend,
                                                  d_cpair, d_dinv, b0, W1, d_hA, N);
    // ---- layer 1: spmm(+b1,relu) fused @W2 -> d_tmp = h1@W2 ----
    spmmG_kernel<true><<<sgrid, 256, 0, stream>>>(d_hA, d_rowbeg, d_rowend,
                                                  d_cpair, d_dinv, b1, W2, d_tmp, N);
    // ---- layer 2: spmm(+b2,relu) -> d_hA = h2 ----
    spmmG_kernel<false><<<sgrid, 256, 0, stream>>>(d_tmp, d_rowbeg, d_rowend,
                                                   d_cpair, d_dinv, b2, nullptr,
                                                   d_hA, N);

    // ---- pool + classifier ----
    pool1_kernel<<<nblk_pool, 256, 0, stream>>>(d_hA, batch, N, B, d_partial);
    pool2_kernel<<<B, 256, 0, stream>>>(d_partial, nblk_pool, B, batch, N, d_pool);
    final_kernel<<<B, 256, 0, stream>>>(d_pool, Wc, bc, (float*)d_out, C);
}